// Round 12
// baseline (54.307 us; speedup 1.0000x reference)
//
#include <hip/hip_runtime.h>
#include <cstdint>

// B=8, L=4096, D=1024, W=128. out[b,l,d] = sort128_window( v[b,(l-d)%L,d] )
constexpr int kL    = 4096;
constexpr int kD    = 1024;
constexpr int kW    = 128;
constexpr int kDT   = 16;          // columns per block (was 32)
constexpr int kROWS = kW + kDT;    // 144 rows (window + halo)
// band = 144*16*4 = 9,216 B; 1 wave/block -> ~17 blocks/CU (~4.25 waves/SIMD,
// 2x R11). Extract is conflict-free with LINEAR layout at kDT=16:
// bank = (s*16+c)&31 = 16*(s&1)+c, s&1 is q-independent -> each half-wave
// hits 16 banks x exactly 2 lanes (free, m136).

// Bitonic sort / merge with all-constant indices (SROA -> registers).
template<int K, int J, int N>
__device__ __forceinline__ void bitonic_stage(float (&e)[N]) {
    #pragma unroll
    for (int i = 0; i < N; ++i) {
        const int ij = i ^ J;
        if (ij > i) {
            const bool up = ((i & K) == 0);
            const float a = e[i], c = e[ij];
            const float lo = fminf(a, c), hi = fmaxf(a, c);
            e[i]  = up ? lo : hi;
            e[ij] = up ? hi : lo;
        }
    }
    if constexpr (J > 1)      bitonic_stage<K, J / 2, N>(e);
    else if constexpr (K < N) bitonic_stage<K * 2, K, N>(e);
}

template<int J, int N>
__device__ __forceinline__ void bitonic_merge(float (&e)[N]) {
    #pragma unroll
    for (int i = 0; i < N; ++i) {
        const int ij = i ^ J;
        if (ij > i) {
            const float a = e[i], c = e[ij];
            e[i]  = fminf(a, c);
            e[ij] = fmaxf(a, c);
        }
    }
    if constexpr (J > 1) bitonic_merge<J / 2, N>(e);
}

__global__ __launch_bounds__(64, 4) void SWD20_sortwin_kernel(
    const float* __restrict__ v, float* __restrict__ out) {
    __shared__ float band[kROWS * kDT];

    const int tid = threadIdx.x;            // = lane (1-wave block)
    // XCD-friendly 1D id: b fastest (xcd=b), then d0-tile, then window ->
    // consecutive same-XCD blocks cover adjacent column tiles of one (w,b):
    // their 64B output half-lines merge to full lines in that XCD's L2.
    const int id  = blockIdx.x;
    const int b   = id & 7;
    const int d0  = ((id >> 3) & 63) * kDT;
    const int w0  = id >> 9;

    const size_t base = (size_t)b * kL * kD;
    const int r_lo = w0 * kW - d0 - (kDT - 1);

    // ---- stage band: 144 rows x 16 cols via direct-to-LDS (9 x 16B/lane).
    // LDS dest wave-uniform (HW adds lane*16); linear granule g = it*64+tid.
    #pragma unroll
    for (int it = 0; it < (kROWS * kDT / 4) / 64; ++it) {
        const int g    = it * 64 + tid;
        const int s    = g >> 2;             // band row (4 float4/row)
        const int slot = g & 3;
        const int gr   = (r_lo + s + 2 * kL) & (kL - 1);
        const float* src = v + base + (size_t)gr * kD + d0 + (slot << 2);
        __builtin_amdgcn_global_load_lds(
            (const __attribute__((address_space(1))) uint32_t*)src,
            (__attribute__((address_space(3))) uint32_t*)&band[it * 256],
            16, 0, 0);
    }
    // single-wave block: own vmcnt(0) makes LDS data visible; no barrier.
    asm volatile("s_waitcnt vmcnt(0)" ::: "memory");

    // ---- 4 lanes per column: lane = q*16 + c; q owns elems [32q, 32q+32) --
    const int q = tid >> 4;                  // quarter (0..3)
    const int c = tid & 15;                  // column within tile
    const int sbase = (kDT - 1) - c + 32 * q;

    // Sign-domain bitonic-128 across 4 lanes (R6/R7-validated derivation):
    //   cross J=32 partner = lane^16 (q^1); cross J=64 partner = lane^32 (q^2)
    const float s0 = (q & 1) ? -1.f : 1.f;
    const float m1 = (q & 2) ? -1.f : 1.f;              // sigma0 -> sigmaA
    const float m2 = (q & 1) ? -1.f : 1.f;              // sigmaA -> sigmaLA
    const float m4 = (q == 1 || q == 2) ? -1.f : 1.f;   // sigmaB -> sigmaC
    const float m5 = (q & 1) ? -1.f : 1.f;              // sigmaC -> real

    float e[32];
    #pragma unroll
    for (int j = 0; j < 32; ++j)
        e[j] = band[(sbase + j) * kDT + c] * s0;

    bitonic_stage<2, 1, 32>(e);                         // local sort-32

    #pragma unroll
    for (int j = 0; j < 32; ++j) e[j] *= m1;
    #pragma unroll
    for (int j = 0; j < 32; ++j)                        // cross K=64 J=32
        e[j] = fminf(e[j], -__shfl_xor(e[j], 16));
    #pragma unroll
    for (int j = 0; j < 32; ++j) e[j] *= m2;
    bitonic_merge<16, 32>(e);                           // local K=64 J<=16

    #pragma unroll
    for (int j = 0; j < 32; ++j)                        // cross K=128 J=64
        e[j] = fminf(e[j], -__shfl_xor(e[j], 32));
    #pragma unroll
    for (int j = 0; j < 32; ++j) e[j] *= m4;
    #pragma unroll
    for (int j = 0; j < 32; ++j)                        // cross K=128 J=32
        e[j] = fminf(e[j], -__shfl_xor(e[j], 16));
    #pragma unroll
    for (int j = 0; j < 32; ++j) e[j] *= m5;
    bitonic_merge<16, 32>(e);                           // final local merge

    // ---- store: fixed j => 4 x 64B segments (4 output rows); cached stores
    // so same-XCD neighbor tiles merge half-lines into full 128B lines in L2.
    float* op = out + base + ((size_t)w0 * kW + 32 * q) * kD + d0 + c;
    #pragma unroll
    for (int j = 0; j < 32; ++j)
        op[(size_t)j * kD] = e[j];
}

extern "C" void kernel_launch(void* const* d_in, const int* in_sizes, int n_in,
                              void* d_out, int out_size, void* d_ws, size_t ws_size,
                              hipStream_t stream) {
    const float* v = (const float*)d_in[2];   // inputs: q, k, v — only v used
    float* out = (float*)d_out;
    const int B = in_sizes[2] / (kL * kD);    // = 8
    const int nblk = (kD / kDT) * (kL / kW) * B;  // 64*32*8 = 16384
    dim3 grid(nblk);                           // 1D: id = b + 8*(d0t + 64*w)
    dim3 block(64);
    hipLaunchKernelGGL(SWD20_sortwin_kernel, grid, block, 0, stream, v, out);
}

// Round 13
// 52.453 us; speedup vs baseline: 1.0354x; 1.0354x over previous
//
#include <hip/hip_runtime.h>
#include <cstdint>

// B=8, L=4096, D=1024, W=128. out[b,l,d] = sort128_window( v[b,(l-d)%L,d] )
// FINAL (R11 config, best: 52.3 us): 1-wave barrier-free blocks, kDT=32,
// global_load_lds staging, XCD-aware remap (xcd = b), cached full-line stores.
// Roofline evidence: R5-R12 swept occupancy (2..17 blk/CU), pipelining,
// nt-vs-cached stores, persistence -- all land 52-56 us at ~197 MB steady
// HBM traffic = ~3.8 TB/s sustained on a 2:1 write:read mix. Reads and
// writes are full-line, conflicts 0, traffic ~1.25x the 262 MB minimum.
constexpr int kL    = 4096;
constexpr int kD    = 1024;
constexpr int kW    = 128;
constexpr int kDT   = 32;   // columns per block
constexpr int kROWS = kW + kDT;   // 159 -> 160 rows (1 window + halo)
// band = 160*32*4 = 20,480 B; 1 wave/block; 8 blocks/CU; no barriers.

// Bitonic sort / merge with all-constant indices (SROA -> registers).
template<int K, int J, int N>
__device__ __forceinline__ void bitonic_stage(float (&e)[N]) {
    #pragma unroll
    for (int i = 0; i < N; ++i) {
        const int ij = i ^ J;
        if (ij > i) {
            const bool up = ((i & K) == 0);
            const float a = e[i], c = e[ij];
            const float lo = fminf(a, c), hi = fmaxf(a, c);
            e[i]  = up ? lo : hi;
            e[ij] = up ? hi : lo;
        }
    }
    if constexpr (J > 1)      bitonic_stage<K, J / 2, N>(e);
    else if constexpr (K < N) bitonic_stage<K * 2, K, N>(e);
}

template<int J, int N>
__device__ __forceinline__ void bitonic_merge(float (&e)[N]) {
    #pragma unroll
    for (int i = 0; i < N; ++i) {
        const int ij = i ^ J;
        if (ij > i) {
            const float a = e[i], c = e[ij];
            e[i]  = fminf(a, c);
            e[ij] = fmaxf(a, c);
        }
    }
    if constexpr (J > 1) bitonic_merge<J / 2, N>(e);
}

__global__ __launch_bounds__(64, 2) void SWD20_sortwin_kernel(
    const float* __restrict__ v, float* __restrict__ out) {
    __shared__ float band[kROWS * kDT];

    const int tid = threadIdx.x;            // = lane (1-wave block)
    // XCD-friendly 1D id: b fastest (xcd = id%8 = b), then d0-tile, then
    // window -> same-XCD blocks share batch working set / L2 locality.
    const int id  = blockIdx.x;
    const int b   = id & 7;
    const int d0  = ((id >> 3) & 31) * kDT;
    const int w0  = id >> 8;

    const size_t base = (size_t)b * kL * kD;
    const int r_lo = w0 * kW - d0 - (kDT - 1);

    // ---- stage band: 160 rows x 32 cols via direct-to-LDS (20 iters).
    // LDS dest wave-uniform (HW adds lane*16); linear layout c = it*64+lane.
    // Per instr: 8 lanes x 16B = 128B contiguous per row -> full-line reads.
    #pragma unroll
    for (int it = 0; it < (kROWS * kDT / 4) / 64; ++it) {
        const int c  = it * 64 + tid;
        const int s  = c >> 3;               // band row (8 float4/row)
        const int fo = (c & 7) << 2;
        const int gr = (r_lo + s + 2 * kL) & (kL - 1);
        const float* src = v + base + (size_t)gr * kD + d0 + fo;
        __builtin_amdgcn_global_load_lds(
            (const __attribute__((address_space(1))) uint32_t*)src,
            (__attribute__((address_space(3))) uint32_t*)&band[it * 256],
            16, 0, 0);
    }
    // single-wave block: own vmcnt(0) makes LDS data visible; no barrier.
    asm volatile("s_waitcnt vmcnt(0)" ::: "memory");

    // ---- 2 lanes per column: lane l elems 0..63, lane l+32 elems 64..127 --
    const int half = tid >> 5;
    const int dl   = tid & 31;
    const int sbase = (kDT - 1) - dl + half * 64;
    const float sgn = half ? -1.0f : 1.0f;  // hi half sorts negated (desc)

    // extract: bank = dl; lane & lane+32 share a bank across half-waves
    // (2-way = free, m136) -> zero conflicts measured.
    float e[64];
    #pragma unroll
    for (int j = 0; j < 64; ++j)
        e[j] = band[(sbase + j) * kDT + dl] * sgn;

    // sort own 64 ascending in storage (hi: real-descending via sign trick)
    bitonic_stage<2, 1, 64>(e);
    // cross-lane stage (j=64 of the 128 network): uniform fminf, no branch
    #pragma unroll
    for (int j = 0; j < 64; ++j) {
        const float r = __shfl_xor(e[j], 32);
        e[j] = fminf(e[j], -r);
    }
    #pragma unroll
    for (int j = 0; j < 64; ++j) e[j] *= sgn;   // restore real values
    bitonic_merge<32, 64>(e);                   // final lane-local merge

    // ---- store: fixed j => two contiguous 128B (full-line) segments.
    float* op = out + base + ((size_t)w0 * kW + half * 64) * kD + d0 + dl;
    #pragma unroll
    for (int j = 0; j < 64; ++j)
        op[(size_t)j * kD] = e[j];
}

extern "C" void kernel_launch(void* const* d_in, const int* in_sizes, int n_in,
                              void* d_out, int out_size, void* d_ws, size_t ws_size,
                              hipStream_t stream) {
    const float* v = (const float*)d_in[2];   // inputs: q, k, v — only v used
    float* out = (float*)d_out;
    const int B = in_sizes[2] / (kL * kD);    // = 8
    const int nblk = (kD / kDT) * (kL / kW) * B;  // 32*32*8 = 8192
    dim3 grid(nblk);                           // 1D: id = b + 8*(d0t + 32*w)
    dim3 block(64);
    hipLaunchKernelGGL(SWD20_sortwin_kernel, grid, block, 0, stream, v, out);
}